// Round 9
// baseline (127.468 us; speedup 1.0000x reference)
//
#include <hip/hip_runtime.h>
#include <math.h>

// Problem constants (match reference)
#define Kp 128
#define Tn 64
#define Dn 128
#define Hn 512
#define RS 136   // ushort row stride for bf16 E rows: 272 B (16B-aligned), +4 banks/row

typedef __attribute__((ext_vector_type(8))) short short8;   // 8 bf16 = 4 VGPRs (MFMA A/B frag)
typedef __attribute__((ext_vector_type(4))) float f32x4;    // MFMA C/D frag

__device__ __forceinline__ float bfpair(unsigned int hi_bits, unsigned int lo_bits) {
    return __uint_as_float(hi_bits) + __uint_as_float(lo_bits);
}

// Serial-chain-minimized variant (R7/R8 counters: 97% idle, latency/clock-bound):
// 6 barriers (was 10), norms fused into pack, xs staging removed, all-thread
// argmax combine, W1/W2 head prefetched right after the pack barrier and pinned
// with sched_barrier so its latency hides under the LDS-only Gram/score phases.
__global__ __launch_bounds__(512, 1) void ep_kernel(
    const int*   __restrict__ Nptr,    // [1]
    const int*   __restrict__ leaf,    // K x 64 (int32)
    const float* __restrict__ emb,     // K x 64 x 128
    const float* __restrict__ W1,      // 256 x 512
    const float* __restrict__ b1,      // 512
    const float* __restrict__ W2,      // 512 x 128
    const float* __restrict__ b2,      // 128
    const float* __restrict__ gum,     // K x 4096
    const float* __restrict__ u1,      // K
    const float* __restrict__ u2,      // K
    float* __restrict__ out)           // 17152 floats
{
    const int k    = blockIdx.x;
    const int tid  = threadIdx.x;
    const int lane = tid & 63;
    const int wid  = tid >> 6;          // 0..7

    __shared__ unsigned short EH[Tn * RS];   // bf16 hi of embeddings, 17408 B
    __shared__ unsigned short EL[Tn * RS];   // bf16 lo residual, 17408 B
    __shared__ float hsh[Hn];        // hidden layer
    __shared__ float buf[2112];      // MLP partials (L1: 4x516, L2: 16x132)
    __shared__ float nI[Tn];         // squared norms (fp32-exact, computed in pack)
    __shared__ float sBest[8]; __shared__ int sIdx[8]; __shared__ float sW[8];
    __shared__ float sSum[8];
    __shared__ float sD1[2]; __shared__ float sD2[2];
    __shared__ int   sLeaf[Tn];
    __shared__ int   sOnes;

    // waves 0-3 -> 2x2 block of 16x16 G-tiles (covers all 4x4 tiles)
    const bool gw   = (wid < 4);
    const int itp   = (wid >> 1) & 1;
    const int jtp   = wid & 1;
    const int lrow  = lane & 15;
    const int lq    = lane >> 4;

    // MLP slice constants
    const int j0  = 4 * (tid & 127);   // L1: 4 owned cols
    const int ih  = tid >> 7;          // L1: i-quarter 0..3
    const int ib  = ih * 64;
    const float* W1r = W1 + j0;
    const int jh  = tid >> 5;          // L2: j-slice 0..15
    const int jb  = jh * 32;
    const int dd4 = 4 * (tid & 31);    // L2: 4 owned d-cols

    // --- ones count + leaf row to LDS (wave 0) ---
    if (tid < 64) {
        int lc = leaf[k * Tn + tid];
        sLeaf[tid] = lc;
        unsigned long long m = __ballot(lc == 1);
        if (tid == 0) sOnes = __popcll(m);
    }

    // --- EARLY global loads ---
    float4 ev[4];
    {
        const float4* src = (const float4*)(emb + (size_t)k * Tn * Dn);
        #pragma unroll
        for (int it = 0; it < 4; ++it) ev[it] = src[tid + it * 512];
    }
    float gv[16];
    if (gw) {
        const float* gk = gum + (size_t)k * (Tn * Tn);
        #pragma unroll
        for (int a = 0; a < 2; ++a)
            #pragma unroll
            for (int b = 0; b < 2; ++b) {
                int it = 2 * itp + a, jt = 2 * jtp + b;
                int col = jt * 16 + lrow;
                #pragma unroll
                for (int r = 0; r < 4; ++r) {
                    int row = it * 16 + lq * 4 + r;
                    gv[(a * 2 + b) * 4 + r] = gk[row * Tn + col];
                }
            }
    }
    float b1v = b1[tid];
    float b2v = (tid < 128) ? b2[tid] : 0.0f;
    float u1v = 0.0f, u2v = 0.0f; int Nv = 0;
    if (tid == 0) { u1v = u1[k]; u2v = u2[k]; Nv = Nptr[0]; }

    // --- pack split-bf16 into LDS + fp32-exact norms via 32-lane reduce ---
    #pragma unroll
    for (int it = 0; it < 4; ++it) {
        int f4 = tid + it * 512;
        int i  = f4 >> 5;
        int d0 = (f4 & 31) << 2;
        float4 v = ev[it];
        unsigned short hx = __float_as_uint(v.x) >> 16, hy = __float_as_uint(v.y) >> 16,
                       hz = __float_as_uint(v.z) >> 16, hw = __float_as_uint(v.w) >> 16;
        float rx = v.x - __uint_as_float((unsigned int)hx << 16);
        float ry = v.y - __uint_as_float((unsigned int)hy << 16);
        float rz = v.z - __uint_as_float((unsigned int)hz << 16);
        float rw = v.w - __uint_as_float((unsigned int)hw << 16);
        unsigned short lx = __float_as_uint(rx) >> 16, ly = __float_as_uint(ry) >> 16,
                       lz = __float_as_uint(rz) >> 16, lw = __float_as_uint(rw) >> 16;
        *(ushort4*)&EH[i * RS + d0] = make_ushort4(hx, hy, hz, hw);
        *(ushort4*)&EL[i * RS + d0] = make_ushort4(lx, ly, lz, lw);
        // norm partial: 32 consecutive lanes hold one row's 32 f4s
        float s = v.x * v.x + v.y * v.y + v.z * v.z + v.w * v.w;
        s += __shfl_down(s, 16, 32);
        s += __shfl_down(s,  8, 32);
        s += __shfl_down(s,  4, 32);
        s += __shfl_down(s,  2, 32);
        s += __shfl_down(s,  1, 32);
        if ((lane & 31) == 0) nI[i] = s;
    }
    __syncthreads();   // (1) EH/EL + nI ready

    // --- W1/W2 head prefetch: issued now (after barrier, so no coupling with
    //     pack's waits); sched_barrier pins issue before the Gram; latency
    //     hides under the LDS-only Gram+score phases. ---
    float4 w1p[16];
    #pragma unroll
    for (int p = 0; p < 16; ++p) w1p[p] = *(const float4*)&W1r[(size_t)(ib + p) * Hn];
    float4 w2p[8];
    #pragma unroll
    for (int p = 0; p < 8; ++p)  w2p[p] = *(const float4*)&W2[(size_t)(jb + p) * Dn + dd4];
    __builtin_amdgcn_sched_barrier(0);

    // --- MFMA Gram (waves 0-3): G = Ehi.Ehi^T + Ehi.Elo^T + Elo.Ehi^T ---
    f32x4 acc[2][2] = {};
    if (gw) {
        const int ka = lq * 8;
        #pragma unroll
        for (int ks = 0; ks < 4; ++ks) {
            int kb  = ks * 32 + ka;
            int ra0 = ((2 * itp + 0) * 16 + lrow) * RS + kb;
            int ra1 = ra0 + 16 * RS;
            int rb0 = ((2 * jtp + 0) * 16 + lrow) * RS + kb;
            int rb1 = rb0 + 16 * RS;
            short8 ah0 = *(const short8*)&EH[ra0], ah1 = *(const short8*)&EH[ra1];
            short8 al0 = *(const short8*)&EL[ra0], al1 = *(const short8*)&EL[ra1];
            short8 bh0 = *(const short8*)&EH[rb0], bh1 = *(const short8*)&EH[rb1];
            short8 bl0 = *(const short8*)&EL[rb0], bl1 = *(const short8*)&EL[rb1];
            acc[0][0] = __builtin_amdgcn_mfma_f32_16x16x32_bf16(ah0, bh0, acc[0][0], 0, 0, 0);
            acc[0][1] = __builtin_amdgcn_mfma_f32_16x16x32_bf16(ah0, bh1, acc[0][1], 0, 0, 0);
            acc[1][0] = __builtin_amdgcn_mfma_f32_16x16x32_bf16(ah1, bh0, acc[1][0], 0, 0, 0);
            acc[1][1] = __builtin_amdgcn_mfma_f32_16x16x32_bf16(ah1, bh1, acc[1][1], 0, 0, 0);
            acc[0][0] = __builtin_amdgcn_mfma_f32_16x16x32_bf16(ah0, bl0, acc[0][0], 0, 0, 0);
            acc[0][1] = __builtin_amdgcn_mfma_f32_16x16x32_bf16(ah0, bl1, acc[0][1], 0, 0, 0);
            acc[1][0] = __builtin_amdgcn_mfma_f32_16x16x32_bf16(ah1, bl0, acc[1][0], 0, 0, 0);
            acc[1][1] = __builtin_amdgcn_mfma_f32_16x16x32_bf16(ah1, bl1, acc[1][1], 0, 0, 0);
            acc[0][0] = __builtin_amdgcn_mfma_f32_16x16x32_bf16(al0, bh0, acc[0][0], 0, 0, 0);
            acc[0][1] = __builtin_amdgcn_mfma_f32_16x16x32_bf16(al0, bh1, acc[0][1], 0, 0, 0);
            acc[1][0] = __builtin_amdgcn_mfma_f32_16x16x32_bf16(al1, bh0, acc[1][0], 0, 0, 0);
            acc[1][1] = __builtin_amdgcn_mfma_f32_16x16x32_bf16(al1, bh1, acc[1][1], 0, 0, 0);
        }
    }

    // --- merge log-weights + argmax(w+g) + expsum (waves 0-3; nI already exact) ---
    float es = 0.0f, best = -INFINITY, bestW = 0.0f;
    int   bestIdx = 0;
    if (gw) {
        #pragma unroll
        for (int a = 0; a < 2; ++a)
            #pragma unroll
            for (int b = 0; b < 2; ++b) {
                int it = 2 * itp + a, jt = 2 * jtp + b;
                int col = jt * 16 + lrow;
                float njc = nI[col];
                f32x4 v = acc[a][b];
                float gvals[4] = {v.x, v.y, v.z, v.w};
                #pragma unroll
                for (int r = 0; r < 4; ++r) {
                    int row = it * 16 + lq * 4 + r;
                    float pd2 = nI[row] + njc - 2.0f * gvals[r];
                    pd2 = fmaxf(pd2, 0.0f) + 1e-12f;
                    float wv = (row == col) ? -INFINITY : -sqrtf(pd2);
                    es += expf(wv);
                    float wg = wv + gv[(a * 2 + b) * 4 + r];
                    int idx = row * Tn + col;
                    if (wg > best || (wg == best && idx < bestIdx)) {
                        best = wg; bestIdx = idx; bestW = wv;
                    }
                }
            }
    }
    #pragma unroll
    for (int off = 32; off > 0; off >>= 1) {
        float ob = __shfl_down(best, off);
        int   oi = __shfl_down(bestIdx, off);
        float ow = __shfl_down(bestW, off);
        float oe = __shfl_down(es, off);
        if (ob > best || (ob == best && oi < bestIdx)) { best = ob; bestIdx = oi; bestW = ow; }
        es += oe;
    }
    if (lane == 0) { sBest[wid] = best; sIdx[wid] = bestIdx; sW[wid] = bestW; sSum[wid] = es; }
    __syncthreads();   // (2) reduction slots ready

    // --- all-thread redundant combine (no extra barrier) ---
    float gBest = sBest[0], gW = sW[0], essum = sSum[0];
    int   gIdx = sIdx[0];
    #pragma unroll
    for (int q = 1; q < 8; ++q) {
        float bq = sBest[q]; int iq = sIdx[q];
        if (bq > gBest || (bq == gBest && iq < gIdx)) { gBest = bq; gIdx = iq; gW = sW[q]; }
        essum += sSum[q];
    }
    const int i1 = gIdx >> 6;
    const int i2 = gIdx & 63;

    // --- MLP layer 1: x reconstructed from EH/EL (wave-uniform -> LDS broadcast);
    //     rows 0-15 from prefetch regs, rest streamed ---
    {
        const int ii    = (ih < 2) ? i1 : i2;
        const int dbase = (ih & 1) * 64;
        const unsigned short* ehr = &EH[ii * RS + dbase];
        const unsigned short* elr = &EL[ii * RS + dbase];
        float4 a = {0, 0, 0, 0};
        #pragma unroll
        for (int r = 0; r < 16; r += 4) {
            uint2 hu = *(const uint2*)&ehr[r];
            uint2 lu = *(const uint2*)&elr[r];
            float x0 = bfpair(hu.x << 16,          lu.x << 16);
            float x1 = bfpair(hu.x & 0xFFFF0000u,  lu.x & 0xFFFF0000u);
            float x2 = bfpair(hu.y << 16,          lu.y << 16);
            float x3 = bfpair(hu.y & 0xFFFF0000u,  lu.y & 0xFFFF0000u);
            float4 w0 = w1p[r + 0], w1 = w1p[r + 1], w2 = w1p[r + 2], w3 = w1p[r + 3];
            a.x += x0 * w0.x + x1 * w1.x + x2 * w2.x + x3 * w3.x;
            a.y += x0 * w0.y + x1 * w1.y + x2 * w2.y + x3 * w3.y;
            a.z += x0 * w0.z + x1 * w1.z + x2 * w2.z + x3 * w3.z;
            a.w += x0 * w0.w + x1 * w1.w + x2 * w2.w + x3 * w3.w;
        }
        #pragma unroll 4
        for (int r = 16; r < 64; r += 4) {
            uint2 hu = *(const uint2*)&ehr[r];
            uint2 lu = *(const uint2*)&elr[r];
            float x0 = bfpair(hu.x << 16,          lu.x << 16);
            float x1 = bfpair(hu.x & 0xFFFF0000u,  lu.x & 0xFFFF0000u);
            float x2 = bfpair(hu.y << 16,          lu.y << 16);
            float x3 = bfpair(hu.y & 0xFFFF0000u,  lu.y & 0xFFFF0000u);
            float4 w0 = *(const float4*)&W1r[(size_t)(ib + r + 0) * Hn];
            float4 w1 = *(const float4*)&W1r[(size_t)(ib + r + 1) * Hn];
            float4 w2 = *(const float4*)&W1r[(size_t)(ib + r + 2) * Hn];
            float4 w3 = *(const float4*)&W1r[(size_t)(ib + r + 3) * Hn];
            a.x += x0 * w0.x + x1 * w1.x + x2 * w2.x + x3 * w3.x;
            a.y += x0 * w0.y + x1 * w1.y + x2 * w2.y + x3 * w3.y;
            a.z += x0 * w0.z + x1 * w1.z + x2 * w2.z + x3 * w3.z;
            a.w += x0 * w0.w + x1 * w1.w + x2 * w2.w + x3 * w3.w;
        }
        *(float4*)&buf[ih * 516 + j0] = a;   // stride 516: %32==4, conflict-free combine
    }
    __syncthreads();   // (3) L1 partials
    hsh[tid] = fmaxf(b1v + buf[tid] + buf[516 + tid]
                     + buf[1032 + tid] + buf[1548 + tid], 0.0f);
    __syncthreads();   // (4) hsh ready

    // --- MLP layer 2: rows jb..jb+7 from prefetch regs, rest streamed ---
    {
        float4 a = {0, 0, 0, 0};
        #pragma unroll
        for (int j = 0; j < 8; j += 4) {
            float4 h4 = *(const float4*)&hsh[jb + j];
            float4 w0 = w2p[j + 0], w1 = w2p[j + 1], w2 = w2p[j + 2], w3 = w2p[j + 3];
            a.x += h4.x * w0.x + h4.y * w1.x + h4.z * w2.x + h4.w * w3.x;
            a.y += h4.x * w0.y + h4.y * w1.y + h4.z * w2.y + h4.w * w3.y;
            a.z += h4.x * w0.z + h4.y * w1.z + h4.z * w2.z + h4.w * w3.z;
            a.w += h4.x * w0.w + h4.y * w1.w + h4.z * w2.w + h4.w * w3.w;
        }
        #pragma unroll 4
        for (int j = 8; j < 32; j += 4) {
            float4 h4 = *(const float4*)&hsh[jb + j];
            float4 w0 = *(const float4*)&W2[(size_t)(jb + j + 0) * Dn + dd4];
            float4 w1 = *(const float4*)&W2[(size_t)(jb + j + 1) * Dn + dd4];
            float4 w2 = *(const float4*)&W2[(size_t)(jb + j + 2) * Dn + dd4];
            float4 w3 = *(const float4*)&W2[(size_t)(jb + j + 3) * Dn + dd4];
            a.x += h4.x * w0.x + h4.y * w1.x + h4.z * w2.x + h4.w * w3.x;
            a.y += h4.x * w0.y + h4.y * w1.y + h4.z * w2.y + h4.w * w3.y;
            a.z += h4.x * w0.z + h4.y * w1.z + h4.z * w2.z + h4.w * w3.z;
            a.w += h4.x * w0.w + h4.y * w1.w + h4.z * w2.w + h4.w * w3.w;
        }
        *(float4*)&buf[jh * 132 + dd4] = a;    // stride 132: %32==4, conflict-free combine
    }
    __syncthreads();   // (5) L2 partials

    // --- embs combine + distances fused (thread d only needs its own E[d]) ---
    if (tid < 128) {
        float e = b2v;
        #pragma unroll
        for (int p = 0; p < 16; ++p) e += buf[p * 132 + tid];
        out[4 * Kp + k * Dn + tid] = e;   // embedding output at offset 512
        float x1d = bfpair((unsigned int)EH[i1 * RS + tid] << 16,
                           (unsigned int)EL[i1 * RS + tid] << 16);
        float x2d = bfpair((unsigned int)EH[i2 * RS + tid] << 16,
                           (unsigned int)EL[i2 * RS + tid] << 16);
        float v1 = (x1d - e) * (x1d - e);
        float v2 = (x2d - e) * (x2d - e);
        #pragma unroll
        for (int off = 32; off > 0; off >>= 1) {
            v1 += __shfl_down(v1, off);
            v2 += __shfl_down(v2, off);
        }
        if (lane == 0) { sD1[wid] = v1; sD2[wid] = v2; }
    }
    __syncthreads();   // (6) distance partials

    // --- scalar epilogue (thread 0) ---
    if (tid == 0) {
        float s1 = sD1[0] + sD1[1];
        float s2 = sD2[0] + sD2[1];
        float d1 = sqrtf(s1 + 1e-12f);
        float d2 = sqrtf(s2 + 1e-12f);
        float rate1 = 1.0f / (d1 + 1e-4f);
        float rate2 = 1.0f / (d2 + 1e-4f);
        float branch1 = -(1.0f / rate1) * logf(u1v);
        float branch2 = -(1.0f / rate2) * logf(u2v);
        float lbp1 = logf(rate1) - rate1 * branch1;
        float lbp2 = logf(rate2) - rate2 * branch2;
        float lse  = logf(essum);                         // direct-sum logsumexp
        float lmp  = gW + 0.69314718055994531f - lse;     // + log(2)
        float lvp  = lmp + lbp1 + lbp2;
        int ones = sOnes - (sLeaf[i1] == 1 ? 1 : 0) - (sLeaf[i2] == 1 ? 1 : 0);
        float lvm = logf((float)(Nv - ones));

        out[k]                         = (float)i1;
        out[Kp + k]                    = (float)i2;
        out[2 * Kp + k]                = branch1;
        out[3 * Kp + k]                = branch2;
        out[4 * Kp + Kp * Dn + k]      = lvp;   // offset 16896
        out[4 * Kp + Kp * Dn + Kp + k] = lvm;   // offset 17024
    }
}

extern "C" void kernel_launch(void* const* d_in, const int* in_sizes, int n_in,
                              void* d_out, int out_size, void* d_ws, size_t ws_size,
                              hipStream_t stream) {
    const int*   Nptr = (const int*)  d_in[0];
    const int*   leaf = (const int*)  d_in[1];
    const float* emb  = (const float*)d_in[2];
    // d_in[3] log_felsensteins, d_in[4] site_positions: unused by reference
    const float* W1   = (const float*)d_in[5];
    const float* b1   = (const float*)d_in[6];
    const float* W2   = (const float*)d_in[7];
    const float* b2   = (const float*)d_in[8];
    const float* gum  = (const float*)d_in[9];
    const float* u1   = (const float*)d_in[10];
    const float* u2   = (const float*)d_in[11];
    float* out = (float*)d_out;

    ep_kernel<<<Kp, 512, 0, stream>>>(Nptr, leaf, emb, W1, b1, W2, b2, gum, u1, u2, out);
}

// Round 10
// 125.332 us; speedup vs baseline: 1.0170x; 1.0170x over previous
//
#include <hip/hip_runtime.h>
#include <math.h>

// Problem constants (match reference)
#define Kp 128
#define Tn 64
#define Dn 128
#define Hn 512
#define RS 136   // ushort row stride for bf16 E rows: 272 B (16B-aligned), +4 banks/row

typedef __attribute__((ext_vector_type(8))) short short8;   // 8 bf16 = 4 VGPRs (MFMA A/B frag)
typedef __attribute__((ext_vector_type(4))) float f32x4;    // MFMA C/D frag

__device__ __forceinline__ float bfpair(unsigned int hi_bits, unsigned int lo_bits) {
    return __uint_as_float(hi_bits) + __uint_as_float(lo_bits);
}

// R9 skeleton + block-staggered weight streams: all blocks previously read the
// SAME W1/W2 lines in lockstep -> 16 same-XCD CUs serialize on the same L2
// banks (convoy). Rotating each block's read order by a per-block offset
// spreads concurrent reads across disjoint regions; every byte still read
// exactly once per block. Only fp32 sum order changes (~1e-5).
__global__ __launch_bounds__(512, 1) void ep_kernel(
    const int*   __restrict__ Nptr,    // [1]
    const int*   __restrict__ leaf,    // K x 64 (int32)
    const float* __restrict__ emb,     // K x 64 x 128
    const float* __restrict__ W1,      // 256 x 512
    const float* __restrict__ b1,      // 512
    const float* __restrict__ W2,      // 512 x 128
    const float* __restrict__ b2,      // 128
    const float* __restrict__ gum,     // K x 4096
    const float* __restrict__ u1,      // K
    const float* __restrict__ u2,      // K
    float* __restrict__ out)           // 17152 floats
{
    const int k    = blockIdx.x;
    const int tid  = threadIdx.x;
    const int lane = tid & 63;
    const int wid  = tid >> 6;          // 0..7

    __shared__ unsigned short EH[Tn * RS];   // bf16 hi of embeddings, 17408 B
    __shared__ unsigned short EL[Tn * RS];   // bf16 lo residual, 17408 B
    __shared__ float hsh[Hn];        // hidden layer
    __shared__ float buf[2112];      // MLP partials (L1: 4x516, L2: 16x132)
    __shared__ float nI[Tn];         // squared norms (fp32-exact, computed in pack)
    __shared__ float sBest[8]; __shared__ int sIdx[8]; __shared__ float sW[8];
    __shared__ float sSum[8];
    __shared__ float sD1[2]; __shared__ float sD2[2];
    __shared__ int   sLeaf[Tn];
    __shared__ int   sOnes;

    // waves 0-3 -> 2x2 block of 16x16 G-tiles (covers all 4x4 tiles)
    const bool gw   = (wid < 4);
    const int itp   = (wid >> 1) & 1;
    const int jtp   = wid & 1;
    const int lrow  = lane & 15;
    const int lq    = lane >> 4;

    // MLP slice constants
    const int j0  = 4 * (tid & 127);   // L1: 4 owned cols
    const int ih  = tid >> 7;          // L1: i-quarter 0..3
    const int ib  = ih * 64;
    const float* W1r = W1 + j0;
    const int jh  = tid >> 5;          // L2: j-slice 0..15
    const int jb  = jh * 32;
    const int dd4 = 4 * (tid & 31);    // L2: 4 owned d-cols

    // per-block stream rotations (same-XCD blocks k = xcd + 8t get distinct t)
    const int rot1 = ((k >> 3) & 15) << 2;   // 0,4,..,60 within the 64-row quarter
    const int rot2 = ((k >> 3) & 7)  << 2;   // 0,4,..,28 within the 32-row slice

    // --- ones count + leaf row to LDS (wave 0) ---
    if (tid < 64) {
        int lc = leaf[k * Tn + tid];
        sLeaf[tid] = lc;
        unsigned long long m = __ballot(lc == 1);
        if (tid == 0) sOnes = __popcll(m);
    }

    // --- EARLY global loads ---
    float4 ev[4];
    {
        const float4* src = (const float4*)(emb + (size_t)k * Tn * Dn);
        #pragma unroll
        for (int it = 0; it < 4; ++it) ev[it] = src[tid + it * 512];
    }
    float gv[16];
    if (gw) {
        const float* gk = gum + (size_t)k * (Tn * Tn);
        #pragma unroll
        for (int a = 0; a < 2; ++a)
            #pragma unroll
            for (int b = 0; b < 2; ++b) {
                int it = 2 * itp + a, jt = 2 * jtp + b;
                int col = jt * 16 + lrow;
                #pragma unroll
                for (int r = 0; r < 4; ++r) {
                    int row = it * 16 + lq * 4 + r;
                    gv[(a * 2 + b) * 4 + r] = gk[row * Tn + col];
                }
            }
    }
    float b1v = b1[tid];
    float b2v = (tid < 128) ? b2[tid] : 0.0f;
    float u1v = 0.0f, u2v = 0.0f; int Nv = 0;
    if (tid == 0) { u1v = u1[k]; u2v = u2[k]; Nv = Nptr[0]; }

    // --- pack split-bf16 into LDS + fp32-exact norms via 32-lane reduce ---
    #pragma unroll
    for (int it = 0; it < 4; ++it) {
        int f4 = tid + it * 512;
        int i  = f4 >> 5;
        int d0 = (f4 & 31) << 2;
        float4 v = ev[it];
        unsigned short hx = __float_as_uint(v.x) >> 16, hy = __float_as_uint(v.y) >> 16,
                       hz = __float_as_uint(v.z) >> 16, hw = __float_as_uint(v.w) >> 16;
        float rx = v.x - __uint_as_float((unsigned int)hx << 16);
        float ry = v.y - __uint_as_float((unsigned int)hy << 16);
        float rz = v.z - __uint_as_float((unsigned int)hz << 16);
        float rw = v.w - __uint_as_float((unsigned int)hw << 16);
        unsigned short lx = __float_as_uint(rx) >> 16, ly = __float_as_uint(ry) >> 16,
                       lz = __float_as_uint(rz) >> 16, lw = __float_as_uint(rw) >> 16;
        *(ushort4*)&EH[i * RS + d0] = make_ushort4(hx, hy, hz, hw);
        *(ushort4*)&EL[i * RS + d0] = make_ushort4(lx, ly, lz, lw);
        // norm partial: 32 consecutive lanes hold one row's 32 f4s
        float s = v.x * v.x + v.y * v.y + v.z * v.z + v.w * v.w;
        s += __shfl_down(s, 16, 32);
        s += __shfl_down(s,  8, 32);
        s += __shfl_down(s,  4, 32);
        s += __shfl_down(s,  2, 32);
        s += __shfl_down(s,  1, 32);
        if ((lane & 31) == 0) nI[i] = s;
    }
    __syncthreads();   // (1) EH/EL + nI ready

    // --- MFMA Gram (waves 0-3): G = Ehi.Ehi^T + Ehi.Elo^T + Elo.Ehi^T ---
    f32x4 acc[2][2] = {};
    if (gw) {
        const int ka = lq * 8;
        #pragma unroll
        for (int ks = 0; ks < 4; ++ks) {
            int kb  = ks * 32 + ka;
            int ra0 = ((2 * itp + 0) * 16 + lrow) * RS + kb;
            int ra1 = ra0 + 16 * RS;
            int rb0 = ((2 * jtp + 0) * 16 + lrow) * RS + kb;
            int rb1 = rb0 + 16 * RS;
            short8 ah0 = *(const short8*)&EH[ra0], ah1 = *(const short8*)&EH[ra1];
            short8 al0 = *(const short8*)&EL[ra0], al1 = *(const short8*)&EL[ra1];
            short8 bh0 = *(const short8*)&EH[rb0], bh1 = *(const short8*)&EH[rb1];
            short8 bl0 = *(const short8*)&EL[rb0], bl1 = *(const short8*)&EL[rb1];
            acc[0][0] = __builtin_amdgcn_mfma_f32_16x16x32_bf16(ah0, bh0, acc[0][0], 0, 0, 0);
            acc[0][1] = __builtin_amdgcn_mfma_f32_16x16x32_bf16(ah0, bh1, acc[0][1], 0, 0, 0);
            acc[1][0] = __builtin_amdgcn_mfma_f32_16x16x32_bf16(ah1, bh0, acc[1][0], 0, 0, 0);
            acc[1][1] = __builtin_amdgcn_mfma_f32_16x16x32_bf16(ah1, bh1, acc[1][1], 0, 0, 0);
            acc[0][0] = __builtin_amdgcn_mfma_f32_16x16x32_bf16(ah0, bl0, acc[0][0], 0, 0, 0);
            acc[0][1] = __builtin_amdgcn_mfma_f32_16x16x32_bf16(ah0, bl1, acc[0][1], 0, 0, 0);
            acc[1][0] = __builtin_amdgcn_mfma_f32_16x16x32_bf16(ah1, bl0, acc[1][0], 0, 0, 0);
            acc[1][1] = __builtin_amdgcn_mfma_f32_16x16x32_bf16(ah1, bl1, acc[1][1], 0, 0, 0);
            acc[0][0] = __builtin_amdgcn_mfma_f32_16x16x32_bf16(al0, bh0, acc[0][0], 0, 0, 0);
            acc[0][1] = __builtin_amdgcn_mfma_f32_16x16x32_bf16(al0, bh1, acc[0][1], 0, 0, 0);
            acc[1][0] = __builtin_amdgcn_mfma_f32_16x16x32_bf16(al1, bh0, acc[1][0], 0, 0, 0);
            acc[1][1] = __builtin_amdgcn_mfma_f32_16x16x32_bf16(al1, bh1, acc[1][1], 0, 0, 0);
        }
    }

    // --- merge log-weights + argmax(w+g) + expsum (waves 0-3) ---
    float es = 0.0f, best = -INFINITY, bestW = 0.0f;
    int   bestIdx = 0;
    if (gw) {
        #pragma unroll
        for (int a = 0; a < 2; ++a)
            #pragma unroll
            for (int b = 0; b < 2; ++b) {
                int it = 2 * itp + a, jt = 2 * jtp + b;
                int col = jt * 16 + lrow;
                float njc = nI[col];
                f32x4 v = acc[a][b];
                float gvals[4] = {v.x, v.y, v.z, v.w};
                #pragma unroll
                for (int r = 0; r < 4; ++r) {
                    int row = it * 16 + lq * 4 + r;
                    float pd2 = nI[row] + njc - 2.0f * gvals[r];
                    pd2 = fmaxf(pd2, 0.0f) + 1e-12f;
                    float wv = (row == col) ? -INFINITY : -sqrtf(pd2);
                    es += expf(wv);
                    float wg = wv + gv[(a * 2 + b) * 4 + r];
                    int idx = row * Tn + col;
                    if (wg > best || (wg == best && idx < bestIdx)) {
                        best = wg; bestIdx = idx; bestW = wv;
                    }
                }
            }
    }
    #pragma unroll
    for (int off = 32; off > 0; off >>= 1) {
        float ob = __shfl_down(best, off);
        int   oi = __shfl_down(bestIdx, off);
        float ow = __shfl_down(bestW, off);
        float oe = __shfl_down(es, off);
        if (ob > best || (ob == best && oi < bestIdx)) { best = ob; bestIdx = oi; bestW = ow; }
        es += oe;
    }
    if (lane == 0) { sBest[wid] = best; sIdx[wid] = bestIdx; sW[wid] = bestW; sSum[wid] = es; }
    __syncthreads();   // (2) reduction slots ready

    // --- all-thread redundant combine (no extra barrier) ---
    float gBest = sBest[0], gW = sW[0], essum = sSum[0];
    int   gIdx = sIdx[0];
    #pragma unroll
    for (int q = 1; q < 8; ++q) {
        float bq = sBest[q]; int iq = sIdx[q];
        if (bq > gBest || (bq == gBest && iq < gIdx)) { gBest = bq; gIdx = iq; gW = sW[q]; }
        essum += sSum[q];
    }
    const int i1 = gIdx >> 6;
    const int i2 = gIdx & 63;

    // --- MLP layer 1: x from EH/EL (wave-uniform LDS broadcast); block-rotated
    //     row order spreads same-XCD blocks across disjoint W1 regions ---
    {
        const int ii    = (ih < 2) ? i1 : i2;
        const int dbase = (ih & 1) * 64;
        const unsigned short* ehr = &EH[ii * RS + dbase];
        const unsigned short* elr = &EL[ii * RS + dbase];
        float4 a = {0, 0, 0, 0};
        #pragma unroll 4
        for (int s = 0; s < 64; s += 4) {
            int r = (rot1 + s) & 63;
            uint2 hu = *(const uint2*)&ehr[r];
            uint2 lu = *(const uint2*)&elr[r];
            float x0 = bfpair(hu.x << 16,          lu.x << 16);
            float x1 = bfpair(hu.x & 0xFFFF0000u,  lu.x & 0xFFFF0000u);
            float x2 = bfpair(hu.y << 16,          lu.y << 16);
            float x3 = bfpair(hu.y & 0xFFFF0000u,  lu.y & 0xFFFF0000u);
            float4 w0 = *(const float4*)&W1r[(size_t)(ib + r + 0) * Hn];
            float4 w1 = *(const float4*)&W1r[(size_t)(ib + r + 1) * Hn];
            float4 w2 = *(const float4*)&W1r[(size_t)(ib + r + 2) * Hn];
            float4 w3 = *(const float4*)&W1r[(size_t)(ib + r + 3) * Hn];
            a.x += x0 * w0.x + x1 * w1.x + x2 * w2.x + x3 * w3.x;
            a.y += x0 * w0.y + x1 * w1.y + x2 * w2.y + x3 * w3.y;
            a.z += x0 * w0.z + x1 * w1.z + x2 * w2.z + x3 * w3.z;
            a.w += x0 * w0.w + x1 * w1.w + x2 * w2.w + x3 * w3.w;
        }
        *(float4*)&buf[ih * 516 + j0] = a;   // stride 516: %32==4, conflict-free combine
    }
    __syncthreads();   // (3) L1 partials
    hsh[tid] = fmaxf(b1v + buf[tid] + buf[516 + tid]
                     + buf[1032 + tid] + buf[1548 + tid], 0.0f);
    __syncthreads();   // (4) hsh ready

    // --- MLP layer 2: block-rotated j order within the slice ---
    {
        float4 a = {0, 0, 0, 0};
        #pragma unroll 4
        for (int s = 0; s < 32; s += 4) {
            int j = (rot2 + s) & 31;
            float4 h4 = *(const float4*)&hsh[jb + j];
            float4 w0 = *(const float4*)&W2[(size_t)(jb + j + 0) * Dn + dd4];
            float4 w1 = *(const float4*)&W2[(size_t)(jb + j + 1) * Dn + dd4];
            float4 w2 = *(const float4*)&W2[(size_t)(jb + j + 2) * Dn + dd4];
            float4 w3 = *(const float4*)&W2[(size_t)(jb + j + 3) * Dn + dd4];
            a.x += h4.x * w0.x + h4.y * w1.x + h4.z * w2.x + h4.w * w3.x;
            a.y += h4.x * w0.y + h4.y * w1.y + h4.z * w2.y + h4.w * w3.y;
            a.z += h4.x * w0.z + h4.y * w1.z + h4.z * w2.z + h4.w * w3.z;
            a.w += h4.x * w0.w + h4.y * w1.w + h4.z * w2.w + h4.w * w3.w;
        }
        *(float4*)&buf[jh * 132 + dd4] = a;    // stride 132: %32==4, conflict-free combine
    }
    __syncthreads();   // (5) L2 partials

    // --- embs combine + distances fused ---
    if (tid < 128) {
        float e = b2v;
        #pragma unroll
        for (int p = 0; p < 16; ++p) e += buf[p * 132 + tid];
        out[4 * Kp + k * Dn + tid] = e;   // embedding output at offset 512
        float x1d = bfpair((unsigned int)EH[i1 * RS + tid] << 16,
                           (unsigned int)EL[i1 * RS + tid] << 16);
        float x2d = bfpair((unsigned int)EH[i2 * RS + tid] << 16,
                           (unsigned int)EL[i2 * RS + tid] << 16);
        float v1 = (x1d - e) * (x1d - e);
        float v2 = (x2d - e) * (x2d - e);
        #pragma unroll
        for (int off = 32; off > 0; off >>= 1) {
            v1 += __shfl_down(v1, off);
            v2 += __shfl_down(v2, off);
        }
        if (lane == 0) { sD1[wid] = v1; sD2[wid] = v2; }
    }
    __syncthreads();   // (6) distance partials

    // --- scalar epilogue (thread 0) ---
    if (tid == 0) {
        float s1 = sD1[0] + sD1[1];
        float s2 = sD2[0] + sD2[1];
        float d1 = sqrtf(s1 + 1e-12f);
        float d2 = sqrtf(s2 + 1e-12f);
        float rate1 = 1.0f / (d1 + 1e-4f);
        float rate2 = 1.0f / (d2 + 1e-4f);
        float branch1 = -(1.0f / rate1) * logf(u1v);
        float branch2 = -(1.0f / rate2) * logf(u2v);
        float lbp1 = logf(rate1) - rate1 * branch1;
        float lbp2 = logf(rate2) - rate2 * branch2;
        float lse  = logf(essum);                         // direct-sum logsumexp
        float lmp  = gW + 0.69314718055994531f - lse;     // + log(2)
        float lvp  = lmp + lbp1 + lbp2;
        int ones = sOnes - (sLeaf[i1] == 1 ? 1 : 0) - (sLeaf[i2] == 1 ? 1 : 0);
        float lvm = logf((float)(Nv - ones));

        out[k]                         = (float)i1;
        out[Kp + k]                    = (float)i2;
        out[2 * Kp + k]                = branch1;
        out[3 * Kp + k]                = branch2;
        out[4 * Kp + Kp * Dn + k]      = lvp;   // offset 16896
        out[4 * Kp + Kp * Dn + Kp + k] = lvm;   // offset 17024
    }
}

extern "C" void kernel_launch(void* const* d_in, const int* in_sizes, int n_in,
                              void* d_out, int out_size, void* d_ws, size_t ws_size,
                              hipStream_t stream) {
    const int*   Nptr = (const int*)  d_in[0];
    const int*   leaf = (const int*)  d_in[1];
    const float* emb  = (const float*)d_in[2];
    // d_in[3] log_felsensteins, d_in[4] site_positions: unused by reference
    const float* W1   = (const float*)d_in[5];
    const float* b1   = (const float*)d_in[6];
    const float* W2   = (const float*)d_in[7];
    const float* b2   = (const float*)d_in[8];
    const float* gum  = (const float*)d_in[9];
    const float* u1   = (const float*)d_in[10];
    const float* u2   = (const float*)d_in[11];
    float* out = (float*)d_out;

    ep_kernel<<<Kp, 512, 0, stream>>>(Nptr, leaf, emb, W1, b1, W2, b2, gum, u1, u2, out);
}